// Round 4
// baseline (81.590 us; speedup 1.0000x reference)
//
#include <hip/hip_runtime.h>

// RNNAdder: out[row] = digits of (a[row] + b[row]) in base 10, MSB-first,
// with a leading final-carry column. a,b (B,2048) f32 digits 0..9;
// out (B,2049) int32.
//
// Persistent grid: 2048 blocks (8/CU), each grid-strides over rows with
// explicit next-row register prefetch so HBM latency hides under the
// current row's scan+stores. Per row: 256 threads, 8 digits/thread,
// wave-local __shfl_up carry scan + 1 barrier for the 4 wave aggregates
// (parity double-buffered LDS).

#define NDIG 2048
#define TPB 256
#define DPT 8
#define NW (TPB / 64)
#define NBLK 2048

__global__ __launch_bounds__(TPB) void rnn_adder_kernel(
    const float* __restrict__ A, const float* __restrict__ B,
    int* __restrict__ out, int rows) {
  const int t = threadIdx.x;
  const int lane = t & 63;
  const int wave = t >> 6;
  const int stride = gridDim.x;
  // t=0 owns the rightmost (least significant) chunk; carry flows t=0 -> 255.
  const int base = NDIG - (t + 1) * DPT;

  __shared__ int wagg[2][NW];

  int r = blockIdx.x;
  if (r >= rows) return;

  // Prologue: load row r.
  const float4* A4 = reinterpret_cast<const float4*>(A + (size_t)r * NDIG + base);
  const float4* B4 = reinterpret_cast<const float4*>(B + (size_t)r * NDIG + base);
  float4 a0 = A4[0], a1 = A4[1], b0 = B4[0], b1 = B4[1];

  int par = 0;
  while (true) {
    // Prefetch next row (wave-uniform branch) before touching current data.
    const int rn = r + stride;
    const bool more = rn < rows;
    float4 na0, na1, nb0, nb1;
    if (more) {
      const float4* nA4 = reinterpret_cast<const float4*>(A + (size_t)rn * NDIG + base);
      const float4* nB4 = reinterpret_cast<const float4*>(B + (size_t)rn * NDIG + base);
      na0 = nA4[0]; na1 = nA4[1]; nb0 = nB4[0]; nb1 = nB4[1];
    }

    int s[DPT];
    s[0] = (int)(a0.x + b0.x);
    s[1] = (int)(a0.y + b0.y);
    s[2] = (int)(a0.z + b0.z);
    s[3] = (int)(a0.w + b0.w);
    s[4] = (int)(a1.x + b1.x);
    s[5] = (int)(a1.y + b1.y);
    s[6] = (int)(a1.z + b1.z);
    s[7] = (int)(a1.w + b1.w);

    // Chunk carry-transfer at cin=0,1. (s+c)>=10 <=> bit5 of (s+c+22).
    int c0 = 0, c1 = 1;
#pragma unroll
    for (int k = DPT - 1; k >= 0; --k) {  // s[DPT-1] is chunk LSB
      c0 = ((s[k] + c0 + 22) >> 5) & 1;
      c1 = ((s[k] + c1 + 22) >> 5) & 1;
    }

    // Packed transfer f: bit0=f(0), bit1=f(1). Identity = 0b10.
    int cur = c0 | (c1 << 1);
#pragma unroll
    for (int off = 1; off < 64; off <<= 1) {
      int prev = __shfl_up(cur, off, 64);
      prev = (lane >= off) ? prev : 2;
      cur = ((cur >> (prev & 1)) & 1) | (((cur >> ((prev >> 1) & 1)) & 1) << 1);
    }

    // Cross-wave aggregate exchange: 1 barrier, parity double-buffer (safe:
    // the next write to this parity slot is 2 iterations away, and the
    // intervening iteration's barrier orders it after this read).
    if (lane == 63) wagg[par][wave] = cur;
    __syncthreads();
    int wc = 0;
#pragma unroll
    for (int w = 0; w < NW; ++w)
      if (w < wave) wc = (wagg[par][w] >> wc) & 1;  // wave-uniform

    int pr = __shfl_up(cur, 1, 64);
    int cin = (lane == 0) ? wc : ((pr >> wc) & 1);

    // Finalize digits (chunk LSB first); reuse s[] as output digits.
    int c = cin;
#pragma unroll
    for (int k = DPT - 1; k >= 0; --k) {
      int v = s[k] + c;
      c = ((v + 22) >> 5) & 1;
      s[k] = v - 10 * c;
    }

    int* orow = out + (size_t)r * (NDIG + 1);
#pragma unroll
    for (int k = 0; k < DPT; ++k) orow[1 + base + k] = s[k];
    if (t == TPB - 1) orow[0] = c;  // final carry (MSB chunk)

    if (!more) break;
    r = rn;
    par ^= 1;
    a0 = na0; a1 = na1; b0 = nb0; b1 = nb1;
  }
}

extern "C" void kernel_launch(void* const* d_in, const int* in_sizes, int n_in,
                              void* d_out, int out_size, void* d_ws, size_t ws_size,
                              hipStream_t stream) {
  const float* A = (const float*)d_in[0];
  const float* B = (const float*)d_in[1];
  int* out = (int*)d_out;
  const int rows = in_sizes[0] / NDIG;
  const int nblk = rows < NBLK ? rows : NBLK;
  rnn_adder_kernel<<<nblk, TPB, 0, stream>>>(A, B, out, rows);
}

// Round 5
// 70.932 us; speedup vs baseline: 1.1503x; 1.1503x over previous
//
#include <hip/hip_runtime.h>

// RNNAdder: out[row] = digits of (a[row] + b[row]) in base 10, MSB-first,
// with a leading final-carry column. a,b (B,2048) f32 digits 0..9;
// out (B,2049) int32.
//
// Block-per-row, 256 threads, 8 digits/thread (R3 structure — ideal
// FETCH/WRITE bytes). Carry scan: wave-local __shfl_up composition scan
// + single LDS exchange of 4 wave aggregates (1 barrier).
// NEW vs R3: nontemporal output stores — the output stream is never
// re-read, so keep it out of L2/L3 to preserve input residency in the
// 256 MB Infinity Cache (FETCH_SIZE showed exactly 50% of reads missing
// to HBM due to output-induced eviction). Dense per-wave 2 KB store
// regions avoid R2's partial-line nt amplification.

#define NDIG 2048
#define TPB 256
#define DPT 8
#define NW (TPB / 64)

__global__ __launch_bounds__(TPB) void rnn_adder_kernel(
    const float* __restrict__ A, const float* __restrict__ B,
    int* __restrict__ out) {
  const int t = threadIdx.x;
  const int lane = t & 63;
  const int wave = t >> 6;
  const int row = blockIdx.x;
  // t=0 owns the rightmost (least significant) chunk; carry flows t=0 -> 255.
  const int base = NDIG - (t + 1) * DPT;

  const float4* A4 = reinterpret_cast<const float4*>(A + (size_t)row * NDIG + base);
  const float4* B4 = reinterpret_cast<const float4*>(B + (size_t)row * NDIG + base);
  float4 a0 = A4[0], a1 = A4[1];
  float4 b0 = B4[0], b1 = B4[1];

  int s[DPT];
  s[0] = (int)(a0.x + b0.x);
  s[1] = (int)(a0.y + b0.y);
  s[2] = (int)(a0.z + b0.z);
  s[3] = (int)(a0.w + b0.w);
  s[4] = (int)(a1.x + b1.x);
  s[5] = (int)(a1.y + b1.y);
  s[6] = (int)(a1.z + b1.z);
  s[7] = (int)(a1.w + b1.w);

  // Chunk carry-transfer evaluated at cin=0,1. s+c in 0..19; (s+c)>=10 <=>
  // bit5 of (s+c+22) -> v_add3 + v_bfe, branch-free.
  int c0 = 0, c1 = 1;
#pragma unroll
  for (int k = DPT - 1; k >= 0; --k) {  // s[DPT-1] is chunk LSB
    c0 = ((s[k] + c0 + 22) >> 5) & 1;
    c1 = ((s[k] + c1 + 22) >> 5) & 1;
  }

  // Packed transfer f: bit0=f(0), bit1=f(1). Identity = 0b10.
  int cur = c0 | (c1 << 1);
  // Inclusive wave-local Kogge-Stone composition scan, barrier-free.
#pragma unroll
  for (int off = 1; off < 64; off <<= 1) {
    int prev = __shfl_up(cur, off, 64);
    prev = (lane >= off) ? prev : 2;
    cur = ((cur >> (prev & 1)) & 1) | (((cur >> ((prev >> 1) & 1)) & 1) << 1);
  }

  // Cross-wave: exchange per-wave aggregate transfers via LDS (1 barrier).
  __shared__ int wagg[NW];
  if (lane == 63) wagg[wave] = cur;
  __syncthreads();

  // Carry into this wave = F_{wave-1} o ... o F_0 applied to 0.
  int wc = 0;
  for (int w = 0; w < wave; ++w) wc = (wagg[w] >> wc) & 1;  // wave-uniform

  // Carry into this thread = (composed transfer of lanes below) applied to wc.
  int pr = __shfl_up(cur, 1, 64);
  int cin = (lane == 0) ? wc : ((pr >> wc) & 1);

  // Finalize digits (chunk LSB first); reuse s[] as output digits.
  int c = cin;
#pragma unroll
  for (int k = DPT - 1; k >= 0; --k) {
    int v = s[k] + c;
    c = ((v + 22) >> 5) & 1;
    s[k] = v - 10 * c;
  }

  int* orow = out + (size_t)row * (NDIG + 1);
#pragma unroll
  for (int k = 0; k < DPT; ++k)
    __builtin_nontemporal_store(s[k], orow + 1 + base + k);
  if (t == TPB - 1) __builtin_nontemporal_store(c, orow);  // final carry
}

extern "C" void kernel_launch(void* const* d_in, const int* in_sizes, int n_in,
                              void* d_out, int out_size, void* d_ws, size_t ws_size,
                              hipStream_t stream) {
  const float* A = (const float*)d_in[0];
  const float* B = (const float*)d_in[1];
  int* out = (int*)d_out;
  const int rows = in_sizes[0] / NDIG;
  rnn_adder_kernel<<<rows, TPB, 0, stream>>>(A, B, out);
}

// Round 7
// 63.670 us; speedup vs baseline: 1.2815x; 1.1141x over previous
//
#include <hip/hip_runtime.h>

// RNNAdder: out[row] = digits of (a[row] + b[row]) in base 10, MSB-first,
// with a leading final-carry column. a,b (B,2048) f32 digits 0..9;
// out (B,2049) int32.
//
// Block-per-row, 256 threads, 8 digits/thread. Carry scan: wave-local
// __shfl_up composition scan + single LDS exchange of wave aggregates.
//
// Output path: rows are 2049 dwords (stride 4 mod 16), so raw per-thread
// nt dword stores left ~20% partial-line write amplification (WRITE_SIZE
// 158 MB vs 131 ideal). Now: stage the row in LDS shifted by (flat & 3)
// so the body can be written as flat-16B-aligned nontemporal 16B stores
// (full-line coverage per instruction); <=3 head / <=3 tail dwords stored
// plain. LDS padded j+(j>>3) to break the stride-8 writer bank pattern.

#define NDIG 2048
#define TPB 256
#define DPT 8
#define NW (TPB / 64)
#define OROW (NDIG + 1)  // 2049 dwords per output row

typedef int iv4 __attribute__((ext_vector_type(4)));

__device__ __forceinline__ int sidx(int j) { return j + (j >> 3); }

__global__ __launch_bounds__(TPB) void rnn_adder_kernel(
    const float* __restrict__ A, const float* __restrict__ B,
    int* __restrict__ out) {
  const int t = threadIdx.x;
  const int lane = t & 63;
  const int wave = t >> 6;
  const int row = blockIdx.x;
  // t=0 owns the rightmost (least significant) chunk; carry flows t=0 -> 255.
  const int base = NDIG - (t + 1) * DPT;

  const float4* A4 = reinterpret_cast<const float4*>(A + (size_t)row * NDIG + base);
  const float4* B4 = reinterpret_cast<const float4*>(B + (size_t)row * NDIG + base);
  float4 a0 = A4[0], a1 = A4[1];
  float4 b0 = B4[0], b1 = B4[1];

  int s[DPT];
  s[0] = (int)(a0.x + b0.x);
  s[1] = (int)(a0.y + b0.y);
  s[2] = (int)(a0.z + b0.z);
  s[3] = (int)(a0.w + b0.w);
  s[4] = (int)(a1.x + b1.x);
  s[5] = (int)(a1.y + b1.y);
  s[6] = (int)(a1.z + b1.z);
  s[7] = (int)(a1.w + b1.w);

  // Chunk carry-transfer evaluated at cin=0,1. (s+c)>=10 <=> bit5 of (s+c+22).
  int c0 = 0, c1 = 1;
#pragma unroll
  for (int k = DPT - 1; k >= 0; --k) {  // s[DPT-1] is chunk LSB
    c0 = ((s[k] + c0 + 22) >> 5) & 1;
    c1 = ((s[k] + c1 + 22) >> 5) & 1;
  }

  // Packed transfer f: bit0=f(0), bit1=f(1). Identity = 0b10.
  int cur = c0 | (c1 << 1);
#pragma unroll
  for (int off = 1; off < 64; off <<= 1) {
    int prev = __shfl_up(cur, off, 64);
    prev = (lane >= off) ? prev : 2;
    cur = ((cur >> (prev & 1)) & 1) | (((cur >> ((prev >> 1) & 1)) & 1) << 1);
  }

  // Cross-wave aggregate exchange (1 barrier).
  __shared__ int wagg[NW];
  if (lane == 63) wagg[wave] = cur;
  __syncthreads();

  int wc = 0;
  for (int w = 0; w < wave; ++w) wc = (wagg[w] >> wc) & 1;  // wave-uniform

  int pr = __shfl_up(cur, 1, 64);
  int cin = (lane == 0) ? wc : ((pr >> wc) & 1);

  // Finalize digits (chunk LSB first); reuse s[] as output digits.
  int c = cin;
#pragma unroll
  for (int k = DPT - 1; k >= 0; --k) {
    int v = s[k] + c;
    c = ((v + 22) >> 5) & 1;
    s[k] = v - 10 * c;
  }

  // ---- Stage row in LDS with per-row alignment shift, store aligned ----
  const size_t S = (size_t)row * OROW;  // flat dword index of this row's carry
  const int shift = (int)(S & 3);       // sd[shift + j] <-> out[S + j]

  __shared__ int sd[2308];  // sidx(3 + 2048) = 2307, +1

#pragma unroll
  for (int k = 0; k < DPT; ++k) sd[sidx(shift + 1 + base + k)] = s[k];
  if (t == TPB - 1) sd[sidx(shift)] = c;  // final carry at out-local 0
  __syncthreads();

  const int j_start = (4 - shift) & 3;        // first out-local j with flat%4==0
  const int ngroups = (OROW - j_start) >> 2;  // 511 or 512 16B groups
  const int jsA = shift + j_start;            // LDS word of first group (0 or 4)

  iv4* dst = reinterpret_cast<iv4*>(out + S + j_start);
  for (int q = t; q < ngroups; q += TPB) {
    const int w = jsA + 4 * q;
    iv4 v = {sd[sidx(w)], sd[sidx(w + 1)], sd[sidx(w + 2)], sd[sidx(w + 3)]};
    __builtin_nontemporal_store(v, dst + q);
  }
  // Head: out-local j in [0, j_start)  (<=3 dwords)
  if (t < j_start) out[S + t] = sd[sidx(shift + t)];
  // Tail: out-local j in [j_start + 4*ngroups, OROW)  (<=3 dwords)
  const int tail0 = j_start + 4 * ngroups;
  const int ntail = OROW - tail0;
  if (t >= 8 && t < 8 + ntail) {
    const int j = tail0 + (t - 8);
    out[S + j] = sd[sidx(shift + j)];
  }
}

extern "C" void kernel_launch(void* const* d_in, const int* in_sizes, int n_in,
                              void* d_out, int out_size, void* d_ws, size_t ws_size,
                              hipStream_t stream) {
  const float* A = (const float*)d_in[0];
  const float* B = (const float*)d_in[1];
  int* out = (int*)d_out;
  const int rows = in_sizes[0] / NDIG;
  rnn_adder_kernel<<<rows, TPB, 0, stream>>>(A, B, out);
}